// Round 2
// baseline (31148.755 us; speedup 1.0000x reference)
//
#include <hip/hip_runtime.h>
#include <cstdint>
#include <cstddef>

#define B_ 64
#define S_ 512
#define IN_ 512
#define H_ 1024
#define NH_ 4
#define HD_ 256
#define A_ 18
#define HID_ 1024
#define TCH_ 128            // scan time-chunk
#define NCH_ (S_ / TCH_)    // 4 chunks

// ---------------- helpers ----------------
__device__ __forceinline__ unsigned short f2bf(float f) {
  union { float f; unsigned u; } c; c.f = f;
  unsigned r = c.u + 0x7FFFu + ((c.u >> 16) & 1u);  // RNE
  return (unsigned short)(r >> 16);
}
__device__ __forceinline__ float bf2f(unsigned short h) {
  union { unsigned u; float f; } c; c.u = ((unsigned)h) << 16;
  return c.f;
}

// ---------------- row stats for LN1 fusion (xproj is bf16) ----------------
__global__ __launch_bounds__(256) void rowstats_k(const unsigned short* __restrict__ x,
                                                  float* __restrict__ rs) {
  const int r = blockIdx.x, tid = threadIdx.x;
  const int lane = tid & 63, wave = tid >> 6;
  ushort4 u = *(const ushort4*)(x + (size_t)r * H_ + tid * 4);
  float v0 = bf2f(u.x), v1 = bf2f(u.y), v2 = bf2f(u.z), v3 = bf2f(u.w);
  float s1 = v0 + v1 + v2 + v3;
  float s2 = v0 * v0 + v1 * v1 + v2 * v2 + v3 * v3;
#pragma unroll
  for (int off = 32; off; off >>= 1) { s1 += __shfl_xor(s1, off); s2 += __shfl_xor(s2, off); }
  __shared__ float a1[4], a2[4];
  if (lane == 0) { a1[wave] = s1; a2[wave] = s2; }
  __syncthreads();
  if (tid == 0) {
    float S1 = a1[0] + a1[1] + a1[2] + a1[3];
    float S2 = a2[0] + a2[1] + a2[2] + a2[3];
    float mu = S1 * (1.f / H_);
    float var = S2 * (1.f / H_) - mu * mu;
    rs[r * 2] = mu;
    rs[r * 2 + 1] = rsqrtf(var + 1e-5f);
  }
}

// ---------------- generic tiled GEMM, fp32 math, bf16 out ----------------
// TRANSB: W is (N,K) row-major.  !TRANSB: W is (K,256) row-major (gate case).
// OUTMODE 0: bf16 row-major out (+bias,+relu), rows = blockIdx.x*128+mm
// OUTMODE 1: bf16 gx chunk layout [sl][b][nh][g][e]; blockIdx.x = b,
//            global row = b*512 + chunk*TCH_ + mm, sl = mm (tile-local)
template <bool TRANSB, bool ABF16, bool LNA, bool RELU, int OUTMODE>
__global__ __launch_bounds__(256) void gemm_k(
    const void* __restrict__ Av, const float* __restrict__ Wt,
    const float* __restrict__ bias, const float* __restrict__ rs,
    const float* __restrict__ lnw, unsigned short* __restrict__ Cb,
    int K, int lda, int ldc, int chunk) {
  __shared__ float As[16][132];
  __shared__ float Bs[16][132];
  const int tid = threadIdx.x;
  const int tx = tid & 15, ty = tid >> 4;
  const int col0 = blockIdx.y * 128;
  int aoff = 0, nh = 0, g = 0;
  const float* W = Wt;
  if constexpr (OUTMODE == 1) {
    int z = blockIdx.z; nh = z >> 2; g = z & 3;
    aoff = nh * HD_;
    W = Wt + (size_t)(g * NH_ + nh) * HD_ * HD_;
  }
  auto arow = [&](int mm) -> int {
    if constexpr (OUTMODE == 1) return (int)blockIdx.x * 512 + chunk * TCH_ + mm;
    else return (int)blockIdx.x * 128 + mm;
  };
  float acc[8][8];
#pragma unroll
  for (int i = 0; i < 8; ++i)
#pragma unroll
    for (int j = 0; j < 8; ++j) acc[i][j] = 0.f;

  for (int k0 = 0; k0 < K; k0 += 16) {
    {  // A tile: As[k][m]
      const int m = tid >> 2;
      const int kq = (tid & 3) * 4;
#pragma unroll
      for (int half = 0; half < 2; ++half) {
        int mm = m + half * 64;
        int rg = arow(mm);
        float av[4];
        if constexpr (ABF16) {
          ushort4 u = *(const ushort4*)((const unsigned short*)Av + (size_t)rg * lda + aoff + k0 + kq);
          av[0] = bf2f(u.x); av[1] = bf2f(u.y); av[2] = bf2f(u.z); av[3] = bf2f(u.w);
        } else {
          float4 f = *(const float4*)((const float*)Av + (size_t)rg * lda + aoff + k0 + kq);
          av[0] = f.x; av[1] = f.y; av[2] = f.z; av[3] = f.w;
        }
        if constexpr (LNA) {
          float mu = rs[rg * 2], rstd = rs[rg * 2 + 1];
#pragma unroll
          for (int j = 0; j < 4; ++j) av[j] = (av[j] - mu) * rstd * lnw[aoff + k0 + kq + j];
        }
#pragma unroll
        for (int j = 0; j < 4; ++j) As[kq + j][mm] = av[j];
      }
    }
    // B tile: Bs[k][n]
    if constexpr (TRANSB) {
      const int nn0 = tid >> 2;
      const int kq = (tid & 3) * 4;
#pragma unroll
      for (int half = 0; half < 2; ++half) {
        int nn = nn0 + half * 64;
        float4 wv = *(const float4*)(W + (size_t)(col0 + nn) * K + k0 + kq);
        Bs[kq + 0][nn] = wv.x; Bs[kq + 1][nn] = wv.y;
        Bs[kq + 2][nn] = wv.z; Bs[kq + 3][nn] = wv.w;
      }
    } else {
      const int kk = tid >> 4;
      const int nn = (tid & 15) * 8;
      const float* wp = W + (size_t)(k0 + kk) * 256 + col0 + nn;
      float4 w0 = *(const float4*)wp;
      float4 w1 = *(const float4*)(wp + 4);
      *(float4*)&Bs[kk][nn] = w0;
      *(float4*)&Bs[kk][nn + 4] = w1;
    }
    __syncthreads();
#pragma unroll
    for (int k = 0; k < 16; ++k) {
      float4 a0 = *(const float4*)&As[k][ty * 4];
      float4 a1 = *(const float4*)&As[k][ty * 4 + 64];
      float4 b0 = *(const float4*)&Bs[k][tx * 4];
      float4 b1 = *(const float4*)&Bs[k][tx * 4 + 64];
      float av[8] = {a0.x, a0.y, a0.z, a0.w, a1.x, a1.y, a1.z, a1.w};
      float bv[8] = {b0.x, b0.y, b0.z, b0.w, b1.x, b1.y, b1.z, b1.w};
#pragma unroll
      for (int i = 0; i < 8; ++i)
#pragma unroll
        for (int j = 0; j < 8; ++j) acc[i][j] = fmaf(av[i], bv[j], acc[i][j]);
    }
    __syncthreads();
  }
  if constexpr (OUTMODE == 0) {
    float4 bia0 = {0, 0, 0, 0}, bia1 = {0, 0, 0, 0};
    if (bias) {
      bia0 = *(const float4*)(bias + col0 + tx * 4);
      bia1 = *(const float4*)(bias + col0 + tx * 4 + 64);
    }
#pragma unroll
    for (int i = 0; i < 8; ++i) {
      int r = arow(ty * 4 + (i & 3) + (i >> 2) * 64);
      float v[8] = {acc[i][0] + bia0.x, acc[i][1] + bia0.y, acc[i][2] + bia0.z, acc[i][3] + bia0.w,
                    acc[i][4] + bia1.x, acc[i][5] + bia1.y, acc[i][6] + bia1.z, acc[i][7] + bia1.w};
      if constexpr (RELU) {
#pragma unroll
        for (int j = 0; j < 8; ++j) v[j] = fmaxf(v[j], 0.f);
      }
      ushort4 s0 = {f2bf(v[0]), f2bf(v[1]), f2bf(v[2]), f2bf(v[3])};
      ushort4 s1 = {f2bf(v[4]), f2bf(v[5]), f2bf(v[6]), f2bf(v[7])};
      *(ushort4*)(Cb + (size_t)r * ldc + col0 + tx * 4) = s0;
      *(ushort4*)(Cb + (size_t)r * ldc + col0 + tx * 4 + 64) = s1;
    }
  } else {
    // gx chunk: idx = ((sl*64+b)*4+nh)*1024_g_e ; sl = tile-local row
    const int b = blockIdx.x;
#pragma unroll
    for (int i = 0; i < 8; ++i) {
      int sl = ty * 4 + (i & 3) + (i >> 2) * 64;
      size_t base = (size_t)(sl * 64 + b) * 4096 + nh * 1024 + g * 256;
#pragma unroll
      for (int q = 0; q < 2; ++q) {
        int e = col0 + tx * 4 + q * 64;
        ushort4 pv = {f2bf(acc[i][q * 4 + 0]), f2bf(acc[i][q * 4 + 1]),
                      f2bf(acc[i][q * 4 + 2]), f2bf(acc[i][q * 4 + 3])};
        *(ushort4*)(Cb + base + e) = pv;
      }
    }
  }
}

// ---------------- sLSTM scan chunk: one block per (batch, head), R in regs ----------------
__global__ __launch_bounds__(1024, 4) void scan_k(
    const unsigned short* __restrict__ gxc, const float* __restrict__ R,
    const float* __restrict__ bgates, float* __restrict__ state,
    unsigned short* __restrict__ y, int chunk) {
  const int tid = threadIdx.x;
  const int nh = blockIdx.x & 3, b = blockIdx.x >> 2;
  const int g = tid >> 8;            // gate owned by this column
  const int e = tid & 255;           // output element
  __shared__ float hsh[256];
  __shared__ float raw[1024];
  float rcol[256];
  {
    // R[nh][d][g][e], d-stride = 1024
    const float* rp = R + ((size_t)nh * 1024 + g) * 256 + e;
#pragma unroll
    for (int d = 0; d < 256; ++d) rcol[d] = rp[(size_t)d * 1024];
  }
  const float bg = bgates[g * H_ + nh * HD_ + e];
  float creg = 0.f, nreg = 0.f, mreg = 0.f, hval = 0.f;
  size_t sb = (size_t)b * H_ + nh * HD_ + (tid & 255);
  if (tid < 256) {
    hval = state[sb];
    creg = state[65536 + sb];
    nreg = state[2 * 65536 + sb];
    mreg = state[3 * 65536 + sb];
    hsh[tid] = hval;
  }
  const unsigned short* gp = gxc + (size_t)b * 4096 + nh * 1024 + tid;
  unsigned short* yp = y + (size_t)chunk * TCH_ * 65536 + b * H_ + nh * HD_;
  unsigned short gcur = gp[0];
  __syncthreads();
  for (int t = 0; t < TCH_; ++t) {
    float acc = bf2f(gcur) + bg;
    if (t < TCH_ - 1) gcur = gp[(size_t)(t + 1) * 262144];  // prefetch under matvec
    const float4* h4 = (const float4*)hsh;
#pragma unroll
    for (int dv = 0; dv < 64; ++dv) {
      float4 hv = h4[dv];
      acc = fmaf(hv.x, rcol[4 * dv + 0], acc);
      acc = fmaf(hv.y, rcol[4 * dv + 1], acc);
      acc = fmaf(hv.z, rcol[4 * dv + 2], acc);
      acc = fmaf(hv.w, rcol[4 * dv + 3], acc);
    }
    raw[tid] = acc;
    __syncthreads();
    if (tid < 256) {
      float iraw = raw[tid], fraw = raw[256 + tid];
      float zraw = raw[512 + tid], oraw = raw[768 + tid];
      float ls = -log1pf(expf(-fabsf(fraw)));
      if (fraw < 0.f) ls += fraw;                   // log_sigmoid(fraw)
      float lfm = mreg + ls;
      float mnew = fmaxf(iraw, lfm);
      float iv = expf(iraw - mnew);
      float fv = expf(lfm - mnew);
      creg = fv * creg + iv * tanhf(zraw);
      nreg = fv * nreg + iv;
      mreg = mnew;
      hval = creg / nreg / (1.f + expf(-oraw));
      hsh[tid] = hval;
      yp[(size_t)t * 65536 + tid] = f2bf(hval);     // y[s][b][h] bf16
    }
    __syncthreads();
  }
  if (tid < 256) {
    state[sb] = hval;
    state[65536 + sb] = creg;
    state[2 * 65536 + sb] = nreg;
    state[3 * 65536 + sb] = mreg;
  }
}

// ---------------- groupnorm + residual + post LN (bf16 in/out) ----------------
__global__ __launch_bounds__(256) void post_k(
    const unsigned short* __restrict__ y, const unsigned short* __restrict__ xp,
    const float* __restrict__ gnw, const float* __restrict__ lpw,
    unsigned short* __restrict__ outb) {
  const int r = blockIdx.x;            // r = b*512 + s
  const int b = r >> 9, s = r & 511;
  const int tid = threadIdx.x;
  const int lane = tid & 63, wave = tid >> 6;
  ushort4 yu = *(const ushort4*)(y + (size_t)(s * 64 + b) * H_ + tid * 4);
  float v[4] = {bf2f(yu.x), bf2f(yu.y), bf2f(yu.z), bf2f(yu.w)};
  float s1 = v[0] + v[1] + v[2] + v[3];
  float s2 = v[0] * v[0] + v[1] * v[1] + v[2] * v[2] + v[3] * v[3];
#pragma unroll
  for (int off = 32; off; off >>= 1) { s1 += __shfl_xor(s1, off); s2 += __shfl_xor(s2, off); }
  float mu = s1 * (1.f / HD_);
  float rstd = rsqrtf(s2 * (1.f / HD_) - mu * mu + 1e-5f);
  float4 g4 = *(const float4*)(gnw + tid * 4);
  ushort4 xu = *(const ushort4*)(xp + (size_t)r * H_ + tid * 4);
  float o[4];
  o[0] = fmaf((v[0] - mu) * rstd, g4.x, bf2f(xu.x));
  o[1] = fmaf((v[1] - mu) * rstd, g4.y, bf2f(xu.y));
  o[2] = fmaf((v[2] - mu) * rstd, g4.z, bf2f(xu.z));
  o[3] = fmaf((v[3] - mu) * rstd, g4.w, bf2f(xu.w));
  float t1 = o[0] + o[1] + o[2] + o[3];
  float t2 = o[0] * o[0] + o[1] * o[1] + o[2] * o[2] + o[3] * o[3];
#pragma unroll
  for (int off = 32; off; off >>= 1) { t1 += __shfl_xor(t1, off); t2 += __shfl_xor(t2, off); }
  __shared__ float a1[4], a2[4];
  if (lane == 0) { a1[wave] = t1; a2[wave] = t2; }
  __syncthreads();
  float T1 = a1[0] + a1[1] + a1[2] + a1[3];
  float T2 = a2[0] + a2[1] + a2[2] + a2[3];
  float MU = T1 * (1.f / H_);
  float RS = rsqrtf(T2 * (1.f / H_) - MU * MU + 1e-5f);
  float4 w4 = *(const float4*)(lpw + tid * 4);
  ushort4 res = {f2bf((o[0] - MU) * RS * w4.x), f2bf((o[1] - MU) * RS * w4.y),
                 f2bf((o[2] - MU) * RS * w4.z), f2bf((o[3] - MU) * RS * w4.w)};
  *(ushort4*)(outb + (size_t)r * H_ + tid * 4) = res;
}

// ---------------- logits + value heads (bf16 in, fp32 out) ----------------
__global__ __launch_bounds__(256) void heads_k(
    const unsigned short* __restrict__ hp, const unsigned short* __restrict__ hv,
    const float* __restrict__ Wact, const float* __restrict__ bact,
    const float* __restrict__ Wv, const float* __restrict__ bv,
    float* __restrict__ dout) {
  const int lane = threadIdx.x & 63, wave = threadIdx.x >> 6;
  const int r = blockIdx.x * 4 + wave;
  const unsigned short* hpr = hp + (size_t)r * HID_;
  const unsigned short* hvr = hv + (size_t)r * HID_;
  float acc[A_];
#pragma unroll
  for (int j = 0; j < A_; ++j) acc[j] = 0.f;
  float accv = 0.f;
  for (int i = 0; i < 16; ++i) {
    int k = i * 64 + lane;
    float hpv = bf2f(hpr[k]);
    float hvv = bf2f(hvr[k]);
#pragma unroll
    for (int j = 0; j < A_; ++j) acc[j] = fmaf(hpv, Wact[j * HID_ + k], acc[j]);
    accv = fmaf(hvv, Wv[k], accv);
  }
#pragma unroll
  for (int j = 0; j < A_; ++j)
#pragma unroll
    for (int off = 32; off; off >>= 1) acc[j] += __shfl_xor(acc[j], off);
#pragma unroll
  for (int off = 32; off; off >>= 1) accv += __shfl_xor(accv, off);
  if (lane == 0) {
#pragma unroll
    for (int j = 0; j < A_; ++j) dout[(size_t)r * A_ + j] = acc[j] + bact[j];
    dout[589824 + r] = accv + bv[0];
  }
}

// ---------------- launch ----------------
extern "C" void kernel_launch(void* const* d_in, const int* in_sizes, int n_in,
                              void* d_out, int out_size, void* d_ws, size_t ws_size,
                              hipStream_t stream) {
  const float* obs   = (const float*)d_in[0];
  const float* st    = (const float*)d_in[1];
  const float* W_in  = (const float*)d_in[2];
  const float* b_in  = (const float*)d_in[3];
  const float* ln1w  = (const float*)d_in[4];
  const float* wg    = (const float*)d_in[5];
  const float* R     = (const float*)d_in[6];
  const float* bgat  = (const float*)d_in[7];
  const float* gnw   = (const float*)d_in[8];
  const float* lpw   = (const float*)d_in[9];
  const float* W_hid = (const float*)d_in[10];
  const float* b_hid = (const float*)d_in[11];
  const float* W_pol = (const float*)d_in[12];
  const float* b_pol = (const float*)d_in[13];
  const float* W_val = (const float*)d_in[14];
  const float* b_val = (const float*)d_in[15];
  const float* W_act = (const float*)d_in[16];
  const float* b_act = (const float*)d_in[17];
  const float* W_v   = (const float*)d_in[18];
  const float* b_v   = (const float*)d_in[19];

  // Workspace layout (bf16 big buffers, heavy overlay):
  //  A [0,        67108864): xproj bf16  -> hh bf16
  //  B [67108864, 134217728): gx chunk bf16 (T=128) -> outb bf16 -> hv bf16
  //  C [134217728,201326592): y bf16 -> hp bf16
  //  ST[201326592,202375168): scan state fp32 (h,c,n,m) 4x64x1024
  //  RS[202375168,202899456): LN1 row stats
  const size_t NEEDED = 202899456;
  if (ws_size < NEEDED) return;  // diagnostic: clean absmax-fail => ws too small
  char* ws = (char*)d_ws;
  unsigned short* xproj = (unsigned short*)(ws + 0);
  unsigned short* gxc   = (unsigned short*)(ws + 67108864);
  unsigned short* ybuf  = (unsigned short*)(ws + 134217728);
  float* statebuf       = (float*)(ws + 201326592);
  float* rstat          = (float*)(ws + 202375168);
  unsigned short* outb  = gxc;    // after last scan chunk
  unsigned short* hh    = xproj;  // after post_k
  unsigned short* hp    = ybuf;   // after MLP1... (y dead after post_k)
  unsigned short* hv    = gxc;    // after MLP1 consumed outb
  float* dout = (float*)d_out;

  // 0. seed scan state
  hipMemcpyAsync(statebuf, st, 4 * 65536 * sizeof(float), hipMemcpyDeviceToDevice, stream);
  // 1. x_proj = obs @ W_in^T + b_in   (M=32768,N=1024,K=512) -> bf16
  gemm_k<true, false, false, false, 0><<<dim3(256, 8), 256, 0, stream>>>(
      obs, W_in, b_in, nullptr, nullptr, xproj, 512, 512, 1024, 0);
  // 2. LN1 row stats
  rowstats_k<<<32768, 256, 0, stream>>>(xproj, rstat);
  // 3+4. per time-chunk: gate GEMM -> scan
  for (int c = 0; c < NCH_; ++c) {
    gemm_k<false, true, true, false, 1><<<dim3(64, 2, 16), 256, 0, stream>>>(
        xproj, wg, nullptr, rstat, ln1w, gxc, 256, 1024, 0, c);
    scan_k<<<256, 1024, 0, stream>>>(gxc, R, bgat, statebuf, ybuf, c);
  }
  // 5. groupnorm + residual + post LN
  post_k<<<32768, 256, 0, stream>>>(ybuf, xproj, gnw, lpw, outb);
  // 6-8. hidden / policy / value MLPs (relu)
  gemm_k<true, true, false, true, 0><<<dim3(256, 8), 256, 0, stream>>>(
      outb, W_hid, b_hid, nullptr, nullptr, hh, 1024, 1024, 1024, 0);
  gemm_k<true, true, false, true, 0><<<dim3(256, 8), 256, 0, stream>>>(
      hh, W_pol, b_pol, nullptr, nullptr, hp, 1024, 1024, 1024, 0);
  gemm_k<true, true, false, true, 0><<<dim3(256, 8), 256, 0, stream>>>(
      hh, W_val, b_val, nullptr, nullptr, hv, 1024, 1024, 1024, 0);
  // 9. logits + value
  heads_k<<<8192, 256, 0, stream>>>(hp, hv, W_act, b_act, W_v, b_v, dout);
}